// Round 15
// baseline (197.340 us; speedup 1.0000x reference)
//
#include <hip/hip_runtime.h>
#include <cstddef>

#define B0V 8
#define HSV 96
#define WSV 96
#define DMV 192
#define DIV 384
#define MTOT (B0V*HSV*WSV)   // 73728

typedef __attribute__((ext_vector_type(8))) unsigned short ushort8v;
typedef __attribute__((ext_vector_type(8))) short short8v;
typedef __attribute__((ext_vector_type(4))) float f32x4;
typedef _Float16 h2 __attribute__((ext_vector_type(2)));
typedef _Float16 h8 __attribute__((ext_vector_type(8)));

__device__ __forceinline__ unsigned short f2bf(float f) {
    unsigned int i; __builtin_memcpy(&i, &f, 4);
    i += 0x7FFFu + ((i >> 16) & 1);
    return (unsigned short)(i >> 16);
}

// ---- LDS staging: tile stored [ROWS][64] bf16, 16B chunks XOR-swizzled by (row&7) ----
template<int ROWS>
__device__ __forceinline__ void stageBF16(const unsigned short* __restrict__ src, int ld,
                                          unsigned short* lds, int t) {
#pragma unroll
    for (int i = 0; i < ROWS*8/256; ++i) {
        const int cid = t + i*256;
        const int r = cid >> 3, cb = cid & 7;
        ushort8v sv = *(const ushort8v*)(src + (size_t)r*ld + cb*8);
        *(ushort8v*)((char*)lds + r*128 + ((cb ^ (r&7))<<4)) = sv;
    }
}
__device__ __forceinline__ short8v fragRead(const unsigned short* lds, int row, int kchunk) {
    return *(const short8v*)((const char*)lds + row*128 + ((kchunk ^ (row&7))<<4));
}

// ---------------- K0: fused prep — wc (192 blk) | wprep (37) | cvt Win (36) | cvt Wout (36) ----------------
__global__ __launch_bounds__(256) void prep_kernel(
    const float* __restrict__ Wout, const float* __restrict__ Win,
    const float* __restrict__ cw,
    unsigned short* __restrict__ Wch, h2* __restrict__ w2h,
    unsigned short* __restrict__ WinfH, unsigned short* __restrict__ WoutH)
{
    const int blk = blockIdx.x;
    const int t = threadIdx.x;
    if (blk < 192) {                       // Wch = W_out @ W_in_z  (bf16 out)
        __shared__ float wrow[384];
        for (int j = t; j < 384; j += 256) wrow[j] = Wout[(size_t)blk*384 + j];
        __syncthreads();
        if (t < 192) {
            float acc = 0.f;
#pragma unroll 4
            for (int j = 0; j < 384; ++j)
                acc += wrow[j] * Win[(size_t)(384 + j)*192 + t];
            Wch[(size_t)blk*192 + t] = f2bf(acc);
        }
    } else if (blk < 229) {                // conv-weight pack f32[384][49] -> h2[49][192]
        const int idx = (blk - 192)*256 + t;
        if (idx < 49*192) {
            const int tap = idx / 192, cp = idx % 192;
            h2 v;
            v[0] = (_Float16)cw[(size_t)(2*cp  )*49 + tap];
            v[1] = (_Float16)cw[(size_t)(2*cp+1)*49 + tap];
            w2h[idx] = v;
        }
    } else if (blk < 265) {                // Win_f -> bf16
        const int i = (blk - 229)*256 + t;
        if (i < 384*192/8) {
            const float4 f0 = *(const float4*)(Win + (size_t)i*8);
            const float4 f1 = *(const float4*)(Win + (size_t)i*8 + 4);
            ushort8v v;
            v[0]=f2bf(f0.x); v[1]=f2bf(f0.y); v[2]=f2bf(f0.z); v[3]=f2bf(f0.w);
            v[4]=f2bf(f1.x); v[5]=f2bf(f1.y); v[6]=f2bf(f1.z); v[7]=f2bf(f1.w);
            *(ushort8v*)(WinfH + (size_t)i*8) = v;
        }
    } else {                               // Wout -> bf16
        const int i = (blk - 265)*256 + t;
        if (i < 192*384/8) {
            const float4 f0 = *(const float4*)(Wout + (size_t)i*8);
            const float4 f1 = *(const float4*)(Wout + (size_t)i*8 + 4);
            ushort8v v;
            v[0]=f2bf(f0.x); v[1]=f2bf(f0.y); v[2]=f2bf(f0.z); v[3]=f2bf(f0.w);
            v[4]=f2bf(f1.x); v[5]=f2bf(f1.y); v[6]=f2bf(f1.z); v[7]=f2bf(f1.w);
            *(ushort8v*)(WoutH + (size_t)i*8) = v;
        }
    }
}

// ---------------- K1: xf(f16, Mx384) = x(f32) @ W_in_f^T(bf16)  (MFMA, 64-row strips) ----------------
__global__ __launch_bounds__(256) void gemm_in_mfma(
    const float* __restrict__ x, const unsigned short* __restrict__ Wh,
    unsigned short* __restrict__ xh, _Float16* __restrict__ xf)
{
    __shared__ unsigned short As[3*64*64];    // 24 KB, resident
    __shared__ unsigned short Bs[128*64];     // 16 KB, streamed
    const int t = threadIdx.x;
    const int m0 = blockIdx.x * 64;
    const int wid = t >> 6, lane = t & 63;
    const int li = lane & 15, lg = lane >> 4;

    // stage A (64x192) once: f32 -> bf16 -> LDS swizzled + xh global
#pragma unroll
    for (int kb = 0; kb < 3; ++kb) {
#pragma unroll
        for (int i = 0; i < 2; ++i) {
            const int cid = t + i*256;
            const int r = cid >> 3, cb = cid & 7;
            const float* p = x + (size_t)(m0 + r)*DMV + kb*64 + cb*8;
            float4 f0 = *(const float4*)p;
            float4 f1 = *(const float4*)(p+4);
            ushort8v sv;
            sv[0]=f2bf(f0.x); sv[1]=f2bf(f0.y); sv[2]=f2bf(f0.z); sv[3]=f2bf(f0.w);
            sv[4]=f2bf(f1.x); sv[5]=f2bf(f1.y); sv[6]=f2bf(f1.z); sv[7]=f2bf(f1.w);
            *(ushort8v*)((char*)(As + kb*64*64) + r*128 + ((cb ^ (r&7))<<4)) = sv;
            *(ushort8v*)(xh + (size_t)(m0 + r)*DMV + kb*64 + cb*8) = sv;
        }
    }

    for (int n0i = 0; n0i < 3; ++n0i) {
        const int n0 = n0i * 128;
        f32x4 acc[4][2];
#pragma unroll
        for (int i = 0; i < 4; ++i)
#pragma unroll
            for (int j = 0; j < 2; ++j) acc[i][j] = (f32x4){0.f,0.f,0.f,0.f};

        for (int kb = 0; kb < 3; ++kb) {
            __syncthreads();
            stageBF16<128>(Wh + (size_t)n0*DMV + kb*64, DMV, Bs, t);
            __syncthreads();
#pragma unroll
            for (int ks = 0; ks < 2; ++ks) {
                short8v a[4], b[2];
#pragma unroll
                for (int mf = 0; mf < 4; ++mf)
                    a[mf] = fragRead(As + kb*64*64, mf*16 + li, ks*4 + lg);
#pragma unroll
                for (int nf = 0; nf < 2; ++nf)
                    b[nf] = fragRead(Bs, wid*32 + nf*16 + li, ks*4 + lg);
#pragma unroll
                for (int mf = 0; mf < 4; ++mf)
#pragma unroll
                    for (int nf = 0; nf < 2; ++nf)
                        acc[mf][nf] = __builtin_amdgcn_mfma_f32_16x16x32_bf16(a[mf], b[nf], acc[mf][nf], 0, 0, 0);
            }
        }
#pragma unroll
        for (int mf = 0; mf < 4; ++mf)
#pragma unroll
            for (int nf = 0; nf < 2; ++nf)
#pragma unroll
                for (int i = 0; i < 4; ++i) {
                    const int row = m0 + mf*16 + lg*4 + i;
                    const int col = n0 + wid*32 + nf*16 + li;
                    xf[(size_t)row*DIV + col] = (_Float16)acc[mf][nf][i];
                }
    }
}

// ---------------- K2: depthwise 7x7 conv — tile-pair + register prefetch (T14) ----------------
// grid 1728; block handles two adjacent 8h x 16w tiles (same row, same cgroup, same batch).
__global__ __launch_bounds__(256) void dwconv_kernel(
    const _Float16* __restrict__ xf, const h2* __restrict__ w2h,
    const float* __restrict__ cb, _Float16* __restrict__ xc)
{
    const int id  = blockIdx.x;                 // 0..1727
    const int swz = (id & 7) * 216 + (id >> 3); // XCD-chunked, bijective (1728%8==0)
    const int T0  = swz * 2;                    // even tile in [0,3456)
    const int b    = T0 / 432;
    const int rem  = T0 - b*432;
    const int cg   = rem / 72;
    const int tile = rem - cg*72;               // even -> tile%6 in {0,2,4}: pair shares row
    const int th = tile / 6, tw = tile % 6;
    const int h0 = th*8;
    const int w0a = tw*16, w0b = w0a + 16;
    const int c0 = cg*64;

    __shared__ _Float16 patch[14*22*64];        // 38.5 KB, linear (conflict-free, measured)
    const int t = threadIdx.x;

    // stage tile A: global -> LDS
    for (int idx = t; idx < 2464; idx += 256) {
        const int sp = idx >> 3, c8 = idx & 7;
        const int ih = sp / 22, iw = sp - ih*22;
        const int gh = h0 - 3 + ih, gw = w0a - 3 + iw;
        ushort8v v;
#pragma unroll
        for (int j = 0; j < 8; ++j) v[j] = 0;
        if ((unsigned)gh < (unsigned)HSV && (unsigned)gw < (unsigned)WSV)
            v = *(const ushort8v*)(xf + (((size_t)b*HSV + gh)*WSV + gw)*DIV + c0 + c8*8);
        *(ushort8v*)(patch + sp*64 + c8*8) = v;
    }

    // prefetch tile B into registers (latency overlaps tile-A drain + compute)
    ushort8v pre[10];
#pragma unroll
    for (int i = 0; i < 10; ++i) {
        const int idx = t + i*256;
        ushort8v v;
#pragma unroll
        for (int j = 0; j < 8; ++j) v[j] = 0;
        if (idx < 2464) {
            const int sp = idx >> 3, c8 = idx & 7;
            const int ih = sp / 22, iw = sp - ih*22;
            const int gh = h0 - 3 + ih, gw = w0b - 3 + iw;
            if ((unsigned)gh < (unsigned)HSV && (unsigned)gw < (unsigned)WSV)
                v = *(const ushort8v*)(xf + (((size_t)b*HSV + gh)*WSV + gw)*DIV + c0 + c8*8);
        }
        pre[i] = v;
    }

    const int cp = t & 31;
    const int wq = t >> 5;

    h2 wreg[49];
    const h2* wp = w2h + (c0 >> 1) + cp;
#pragma unroll
    for (int k = 0; k < 49; ++k) wreg[k] = wp[k*192];

    h2 biasv;
    biasv[0] = (_Float16)cb[c0 + 2*cp];
    biasv[1] = (_Float16)cb[c0 + 2*cp + 1];

    h2* xcp = (h2*)xc;
    const h2* prow = (const h2*)patch;

    auto compute_store = [&](int w0) {
        h2 acc[8][2];
#pragma unroll
        for (int i = 0; i < 8; ++i) { acc[i][0] = biasv; acc[i][1] = biasv; }
#pragma unroll
        for (int ih = 0; ih < 14; ++ih) {
            h2 r[8];
#pragma unroll
            for (int j = 0; j < 8; ++j)
                r[j] = prow[(ih*22 + wq*2 + j)*32 + cp];
#pragma unroll
            for (int kw = 0; kw < 7; ++kw) {
#pragma unroll
                for (int oh = 0; oh < 8; ++oh) {
                    const int kh = ih - oh;
                    if (kh >= 0 && kh < 7) {
                        acc[oh][0] += wreg[kh*7 + kw] * r[kw];
                        acc[oh][1] += wreg[kh*7 + kw] * r[kw + 1];
                    }
                }
            }
        }
#pragma unroll
        for (int oh = 0; oh < 8; ++oh)
#pragma unroll
            for (int j = 0; j < 2; ++j)
                xcp[((((size_t)b*HSV + h0+oh)*WSV + (w0 + wq*2 + j))*DIV + c0)/2 + cp] = acc[oh][j];
    };

    __syncthreads();
    compute_store(w0a);
    __syncthreads();

    // write prefetched tile B regs -> LDS
#pragma unroll
    for (int i = 0; i < 10; ++i) {
        const int idx = t + i*256;
        if (idx < 2464) {
            const int sp = idx >> 3, c8 = idx & 7;
            *(ushort8v*)(patch + sp*64 + c8*8) = pre[i];
        }
    }
    __syncthreads();
    compute_store(w0b);
}

// ---------------- K3: dilated 3x3 box-sum + LayerNorm — wave per pixel (standalone) ----------------
__global__ __launch_bounds__(256) void boxln_kernel(
    const _Float16* __restrict__ xc,
    const float* __restrict__ g, const float* __restrict__ bta,
    unsigned short* __restrict__ yln)
{
    const int wid  = threadIdx.x >> 6;
    const int lane = threadIdx.x & 63;
    const int m = blockIdx.x * 4 + wid;
    const int b  = m / (HSV*WSV);
    const int hw = m % (HSV*WSV);
    const int h = hw / WSV, w = hw % WSV;

    const bool act = lane < 48;
    const int ch = lane * 8;
    const int dd = (ch >> 7) + 1;

    float s[8];
#pragma unroll
    for (int j = 0; j < 8; ++j) s[j] = 0.f;

#pragma unroll
    for (int a = -1; a <= 1; ++a)
#pragma unroll
        for (int bb = -1; bb <= 1; ++bb) {
            const int h2_ = h + a*dd, w2_ = w + bb*dd;
            if (act && (unsigned)h2_ < (unsigned)HSV && (unsigned)w2_ < (unsigned)WSV) {
                h8 v = *(const h8*)(xc + (((size_t)b*HSV + h2_)*WSV + w2_)*DIV + ch);
#pragma unroll
                for (int j = 0; j < 8; ++j) s[j] += (float)v[j];
            }
        }

    float ps = 0.f, ps2 = 0.f;
#pragma unroll
    for (int j = 0; j < 8; ++j) { ps += s[j]; ps2 += s[j]*s[j]; }
#pragma unroll
    for (int off = 32; off > 0; off >>= 1) {
        ps  += __shfl_xor(ps,  off);
        ps2 += __shfl_xor(ps2, off);
    }
    const float mu   = ps * (1.f/384.f);
    const float var  = ps2 * (1.f/384.f) - mu*mu;
    const float rstd = rsqrtf(var + 1e-5f);

    if (act) {
        float4 g0 = *(const float4*)(g + ch);
        float4 g1 = *(const float4*)(g + ch + 4);
        float4 b0 = *(const float4*)(bta + ch);
        float4 b1 = *(const float4*)(bta + ch + 4);
        float gv[8] = {g0.x,g0.y,g0.z,g0.w,g1.x,g1.y,g1.z,g1.w};
        float bv[8] = {b0.x,b0.y,b0.z,b0.w,b1.x,b1.y,b1.z,b1.w};
        ushort8v o;
#pragma unroll
        for (int j = 0; j < 8; ++j)
            o[j] = f2bf((s[j] - mu)*rstd*gv[j] + bv[j]);
        *(ushort8v*)(yln + (size_t)m*DIV + ch) = o;
    }
}

// ---------------- K4: out(f32, Mx192) = yln @ WoutH^T + xh @ Wch^T  (MFMA, 128-row strips) ----------------
__global__ __launch_bounds__(256) void gemm_out_mfma(
    const unsigned short* __restrict__ Yl, const unsigned short* __restrict__ WoutH,
    const unsigned short* __restrict__ xh, const unsigned short* __restrict__ Wch,
    float* __restrict__ out)
{
    __shared__ unsigned short As[128*64];     // 16 KB
    __shared__ unsigned short Bs[192*64];     // 24 KB
    const int t = threadIdx.x;
    const int m0 = blockIdx.x * 128;
    const int wid = t >> 6, lane = t & 63;
    const int wm = wid >> 1, wn = wid & 1;
    const int li = lane & 15, lg = lane >> 4;

    f32x4 acc[4][6];
#pragma unroll
    for (int i = 0; i < 4; ++i)
#pragma unroll
        for (int j = 0; j < 6; ++j) acc[i][j] = (f32x4){0.f,0.f,0.f,0.f};

    for (int kb = 0; kb < 9; ++kb) {
        if (kb < 6) {
            stageBF16<128>(Yl + (size_t)m0*DIV + kb*64, DIV, As, t);
            stageBF16<192>(WoutH + kb*64, DIV, Bs, t);
        } else {
            stageBF16<128>(xh + (size_t)m0*DMV + (kb-6)*64, DMV, As, t);
            stageBF16<192>(Wch + (kb-6)*64, DMV, Bs, t);
        }
        __syncthreads();
#pragma unroll
        for (int ks = 0; ks < 2; ++ks) {
            short8v a[4], b[6];
#pragma unroll
            for (int mf = 0; mf < 4; ++mf) a[mf] = fragRead(As, wm*64 + mf*16 + li, ks*4 + lg);
#pragma unroll
            for (int nf = 0; nf < 6; ++nf) b[nf] = fragRead(Bs, wn*96 + nf*16 + li, ks*4 + lg);
#pragma unroll
            for (int mf = 0; mf < 4; ++mf)
#pragma unroll
                for (int nf = 0; nf < 6; ++nf)
                    acc[mf][nf] = __builtin_amdgcn_mfma_f32_16x16x32_bf16(a[mf], b[nf], acc[mf][nf], 0, 0, 0);
        }
        __syncthreads();
    }
#pragma unroll
    for (int mf = 0; mf < 4; ++mf)
#pragma unroll
        for (int nf = 0; nf < 6; ++nf)
#pragma unroll
            for (int i = 0; i < 4; ++i) {
                const int row = m0 + wm*64 + mf*16 + lg*4 + i;
                const int col = wn*96 + nf*16 + li;
                out[(size_t)row*DMV + col] = acc[mf][nf][i];
            }
}

extern "C" void kernel_launch(void* const* d_in, const int* in_sizes, int n_in,
                              void* d_out, int out_size, void* d_ws, size_t ws_size,
                              hipStream_t stream)
{
    const float* x      = (const float*)d_in[0];
    const float* W_in   = (const float*)d_in[1];
    const float* conv_w = (const float*)d_in[2];
    const float* conv_b = (const float*)d_in[3];
    const float* ln_g   = (const float*)d_in[11];
    const float* ln_b   = (const float*)d_in[12];
    const float* W_out  = (const float*)d_in[13];
    float* out = (float*)d_out;

    // ws (~90.2 MB): Wch | w2h | WinfH | WoutH | xh | xf(=yln).  xc aliases d_out.
    char* ws = (char*)d_ws;
    unsigned short* Wch   = (unsigned short*)(ws);              // 192*192 bf16
    h2*             w2h   = (h2*)(ws + 0x20000);                // 49*192 h2
    unsigned short* WinfH = (unsigned short*)(ws + 0x40000);    // 384*192 bf16
    unsigned short* WoutH = (unsigned short*)(ws + 0x80000);    // 192*384 bf16
    unsigned short* xh    = (unsigned short*)(ws + 0x100000);   // M*192 bf16
    _Float16*       xf    = (_Float16*)(ws + 0x2000000);        // M*384 f16 (reused as bf16 yln)
    _Float16*       xc    = (_Float16*)d_out;                   // M*384 f16 aliased on out

    prep_kernel  <<<dim3(301),          256, 0, stream>>>(W_out, W_in, conv_w,
                                                          Wch, w2h, WinfH, WoutH);
    gemm_in_mfma <<<dim3(MTOT/64),      256, 0, stream>>>(x, WinfH, xh, xf);
    dwconv_kernel<<<dim3(1728),         256, 0, stream>>>(xf, w2h, conv_b, xc);
    boxln_kernel <<<dim3(MTOT/4),       256, 0, stream>>>(xc, ln_g, ln_b,
                                                          (unsigned short*)xf);
    gemm_out_mfma<<<dim3(MTOT/128),     256, 0, stream>>>((const unsigned short*)xf,
                                                          WoutH, xh, Wch, out);
}

// Round 16
// 183.614 us; speedup vs baseline: 1.0748x; 1.0748x over previous
//
#include <hip/hip_runtime.h>
#include <cstddef>

#define B0V 8
#define HSV 96
#define WSV 96
#define DMV 192
#define DIV 384
#define MTOT (B0V*HSV*WSV)   // 73728

typedef __attribute__((ext_vector_type(8))) unsigned short ushort8v;
typedef __attribute__((ext_vector_type(8))) short short8v;
typedef __attribute__((ext_vector_type(4))) float f32x4;
typedef _Float16 h2 __attribute__((ext_vector_type(2)));
typedef _Float16 h8 __attribute__((ext_vector_type(8)));

__device__ __forceinline__ unsigned short f2bf(float f) {
    unsigned int i; __builtin_memcpy(&i, &f, 4);
    i += 0x7FFFu + ((i >> 16) & 1);
    return (unsigned short)(i >> 16);
}

// ---- LDS staging: tile stored [ROWS][64] bf16, 16B chunks XOR-swizzled by (row&7) ----
template<int ROWS>
__device__ __forceinline__ void stageBF16(const unsigned short* __restrict__ src, int ld,
                                          unsigned short* lds, int t) {
#pragma unroll
    for (int i = 0; i < ROWS*8/256; ++i) {
        const int cid = t + i*256;
        const int r = cid >> 3, cb = cid & 7;
        ushort8v sv = *(const ushort8v*)(src + (size_t)r*ld + cb*8);
        *(ushort8v*)((char*)lds + r*128 + ((cb ^ (r&7))<<4)) = sv;
    }
}
// split form: load global -> regs, and regs -> LDS (same indexing)
template<int ROWS>
__device__ __forceinline__ void loadRegs(const unsigned short* __restrict__ src, int ld,
                                         int t, ushort8v* r) {
#pragma unroll
    for (int i = 0; i < ROWS*8/256; ++i) {
        const int cid = t + i*256;
        const int rr = cid >> 3, cb = cid & 7;
        r[i] = *(const ushort8v*)(src + (size_t)rr*ld + cb*8);
    }
}
template<int ROWS>
__device__ __forceinline__ void writeRegs(unsigned short* lds, int t, const ushort8v* r) {
#pragma unroll
    for (int i = 0; i < ROWS*8/256; ++i) {
        const int cid = t + i*256;
        const int rr = cid >> 3, cb = cid & 7;
        *(ushort8v*)((char*)lds + rr*128 + ((cb ^ (rr&7))<<4)) = r[i];
    }
}
__device__ __forceinline__ short8v fragRead(const unsigned short* lds, int row, int kchunk) {
    return *(const short8v*)((const char*)lds + row*128 + ((kchunk ^ (row&7))<<4));
}

// ---------------- K0: fused prep — wc (192 blk) | wprep (37) | cvt Win (36) | cvt Wout (36) ----------------
__global__ __launch_bounds__(256) void prep_kernel(
    const float* __restrict__ Wout, const float* __restrict__ Win,
    const float* __restrict__ cw,
    unsigned short* __restrict__ Wch, h2* __restrict__ w2h,
    unsigned short* __restrict__ WinfH, unsigned short* __restrict__ WoutH)
{
    const int blk = blockIdx.x;
    const int t = threadIdx.x;
    if (blk < 192) {                       // Wch = W_out @ W_in_z  (bf16 out)
        __shared__ float wrow[384];
        for (int j = t; j < 384; j += 256) wrow[j] = Wout[(size_t)blk*384 + j];
        __syncthreads();
        if (t < 192) {
            float acc = 0.f;
#pragma unroll 4
            for (int j = 0; j < 384; ++j)
                acc += wrow[j] * Win[(size_t)(384 + j)*192 + t];
            Wch[(size_t)blk*192 + t] = f2bf(acc);
        }
    } else if (blk < 229) {                // conv-weight pack f32[384][49] -> h2[49][192]
        const int idx = (blk - 192)*256 + t;
        if (idx < 49*192) {
            const int tap = idx / 192, cp = idx % 192;
            h2 v;
            v[0] = (_Float16)cw[(size_t)(2*cp  )*49 + tap];
            v[1] = (_Float16)cw[(size_t)(2*cp+1)*49 + tap];
            w2h[idx] = v;
        }
    } else if (blk < 265) {                // Win_f -> bf16
        const int i = (blk - 229)*256 + t;
        if (i < 384*192/8) {
            const float4 f0 = *(const float4*)(Win + (size_t)i*8);
            const float4 f1 = *(const float4*)(Win + (size_t)i*8 + 4);
            ushort8v v;
            v[0]=f2bf(f0.x); v[1]=f2bf(f0.y); v[2]=f2bf(f0.z); v[3]=f2bf(f0.w);
            v[4]=f2bf(f1.x); v[5]=f2bf(f1.y); v[6]=f2bf(f1.z); v[7]=f2bf(f1.w);
            *(ushort8v*)(WinfH + (size_t)i*8) = v;
        }
    } else {                               // Wout -> bf16
        const int i = (blk - 265)*256 + t;
        if (i < 192*384/8) {
            const float4 f0 = *(const float4*)(Wout + (size_t)i*8);
            const float4 f1 = *(const float4*)(Wout + (size_t)i*8 + 4);
            ushort8v v;
            v[0]=f2bf(f0.x); v[1]=f2bf(f0.y); v[2]=f2bf(f0.z); v[3]=f2bf(f0.w);
            v[4]=f2bf(f1.x); v[5]=f2bf(f1.y); v[6]=f2bf(f1.z); v[7]=f2bf(f1.w);
            *(ushort8v*)(WoutH + (size_t)i*8) = v;
        }
    }
}

// ---------------- K1: xf(f16, Mx384) = x(f32) @ W_in_f^T(bf16)  (MFMA, 64-row strips) ----------------
// A resident; B streamed with async-STAGE register prefetch (next-B load hides under MFMA).
__global__ __launch_bounds__(256) void gemm_in_mfma(
    const float* __restrict__ x, const unsigned short* __restrict__ Wh,
    unsigned short* __restrict__ xh, _Float16* __restrict__ xf)
{
    __shared__ unsigned short As[3*64*64];    // 24 KB, resident
    __shared__ unsigned short Bs[128*64];     // 16 KB, streamed
    const int t = threadIdx.x;
    const int m0 = blockIdx.x * 64;
    const int wid = t >> 6, lane = t & 63;
    const int li = lane & 15, lg = lane >> 4;

    // stage A (64x192) once: f32 -> bf16 -> LDS swizzled + xh global
#pragma unroll
    for (int kb = 0; kb < 3; ++kb) {
#pragma unroll
        for (int i = 0; i < 2; ++i) {
            const int cid = t + i*256;
            const int r = cid >> 3, cb = cid & 7;
            const float* p = x + (size_t)(m0 + r)*DMV + kb*64 + cb*8;
            float4 f0 = *(const float4*)p;
            float4 f1 = *(const float4*)(p+4);
            ushort8v sv;
            sv[0]=f2bf(f0.x); sv[1]=f2bf(f0.y); sv[2]=f2bf(f0.z); sv[3]=f2bf(f0.w);
            sv[4]=f2bf(f1.x); sv[5]=f2bf(f1.y); sv[6]=f2bf(f1.z); sv[7]=f2bf(f1.w);
            *(ushort8v*)((char*)(As + kb*64*64) + r*128 + ((cb ^ (r&7))<<4)) = sv;
            *(ushort8v*)(xh + (size_t)(m0 + r)*DMV + kb*64 + cb*8) = sv;
        }
    }

    ushort8v pb[4];
    loadRegs<128>(Wh, DMV, t, pb);            // (n0=0, kb=0)

    f32x4 acc[4][2];
    for (int it = 0; it < 9; ++it) {
        const int n0i = it / 3, kb = it - n0i*3;
        const int n0 = n0i * 128;
        if (kb == 0) {
#pragma unroll
            for (int i = 0; i < 4; ++i)
#pragma unroll
                for (int j = 0; j < 2; ++j) acc[i][j] = (f32x4){0.f,0.f,0.f,0.f};
        }
        writeRegs<128>(Bs, t, pb);
        __syncthreads();
        if (it < 8) {
            const int itn = it + 1;
            loadRegs<128>(Wh + (size_t)((itn/3)*128)*DMV + (itn%3)*64, DMV, t, pb);
        }
#pragma unroll
        for (int ks = 0; ks < 2; ++ks) {
            short8v a[4], b[2];
#pragma unroll
            for (int mf = 0; mf < 4; ++mf)
                a[mf] = fragRead(As + kb*64*64, mf*16 + li, ks*4 + lg);
#pragma unroll
            for (int nf = 0; nf < 2; ++nf)
                b[nf] = fragRead(Bs, wid*32 + nf*16 + li, ks*4 + lg);
#pragma unroll
            for (int mf = 0; mf < 4; ++mf)
#pragma unroll
                for (int nf = 0; nf < 2; ++nf)
                    acc[mf][nf] = __builtin_amdgcn_mfma_f32_16x16x32_bf16(a[mf], b[nf], acc[mf][nf], 0, 0, 0);
        }
        __syncthreads();
        if (kb == 2) {
#pragma unroll
            for (int mf = 0; mf < 4; ++mf)
#pragma unroll
                for (int nf = 0; nf < 2; ++nf)
#pragma unroll
                    for (int i = 0; i < 4; ++i) {
                        const int row = m0 + mf*16 + lg*4 + i;
                        const int col = n0 + wid*32 + nf*16 + li;
                        xf[(size_t)row*DIV + col] = (_Float16)acc[mf][nf][i];
                    }
        }
    }
}

// ---------------- K2: depthwise 7x7 conv — R14 exact: R6 tiling + XCD-chunked swizzle ----------------
__global__ __launch_bounds__(256) void dwconv_kernel(
    const _Float16* __restrict__ xf, const h2* __restrict__ w2h,
    const float* __restrict__ cb, _Float16* __restrict__ xc)
{
    const int id  = blockIdx.x;
    const int swz = (id & 7) * 432 + (id >> 3);
    const int b    = swz / 432;
    const int rem  = swz - b*432;
    const int cg   = rem / 72;
    const int tile = rem - cg*72;
    const int th = tile / 6, tw = tile % 6;
    const int h0 = th*8, w0 = tw*16;
    const int c0 = cg*64;

    __shared__ _Float16 patch[14*22*64];    // 38.5 KB, linear (conflict-free, measured)
    const int t = threadIdx.x;
    for (int idx = t; idx < 308*8; idx += 256) {
        const int sp = idx >> 3, c8 = idx & 7;
        const int ih = sp / 22, iw = sp - ih*22;
        const int gh = h0 - 3 + ih, gw = w0 - 3 + iw;
        ushort8v v;
#pragma unroll
        for (int j = 0; j < 8; ++j) v[j] = 0;
        if ((unsigned)gh < (unsigned)HSV && (unsigned)gw < (unsigned)WSV)
            v = *(const ushort8v*)(xf + (((size_t)b*HSV + gh)*WSV + gw)*DIV + c0 + c8*8);
        *(ushort8v*)(patch + sp*64 + c8*8) = v;
    }
    __syncthreads();

    const int cp = t & 31;
    const int wq = t >> 5;

    h2 wreg[49];
    const h2* wp = w2h + (c0 >> 1) + cp;
#pragma unroll
    for (int k = 0; k < 49; ++k) wreg[k] = wp[k*192];

    h2 biasv;
    biasv[0] = (_Float16)cb[c0 + 2*cp];
    biasv[1] = (_Float16)cb[c0 + 2*cp + 1];
    h2 acc[8][2];
#pragma unroll
    for (int i = 0; i < 8; ++i) { acc[i][0] = biasv; acc[i][1] = biasv; }

    const h2* prow = (const h2*)patch;
#pragma unroll
    for (int ih = 0; ih < 14; ++ih) {
        h2 r[8];
#pragma unroll
        for (int j = 0; j < 8; ++j)
            r[j] = prow[(ih*22 + wq*2 + j)*32 + cp];
#pragma unroll
        for (int kw = 0; kw < 7; ++kw) {
#pragma unroll
            for (int oh = 0; oh < 8; ++oh) {
                const int kh = ih - oh;
                if (kh >= 0 && kh < 7) {
                    acc[oh][0] += wreg[kh*7 + kw] * r[kw];
                    acc[oh][1] += wreg[kh*7 + kw] * r[kw + 1];
                }
            }
        }
    }
    h2* xcp = (h2*)xc;
#pragma unroll
    for (int oh = 0; oh < 8; ++oh)
#pragma unroll
        for (int j = 0; j < 2; ++j)
            xcp[((((size_t)b*HSV + h0+oh)*WSV + (w0 + wq*2 + j))*DIV + c0)/2 + cp] = acc[oh][j];
}

// ---------------- K3: dilated 3x3 box-sum + LayerNorm — wave per pixel (standalone) ----------------
__global__ __launch_bounds__(256) void boxln_kernel(
    const _Float16* __restrict__ xc,
    const float* __restrict__ g, const float* __restrict__ bta,
    unsigned short* __restrict__ yln)
{
    const int wid  = threadIdx.x >> 6;
    const int lane = threadIdx.x & 63;
    const int m = blockIdx.x * 4 + wid;
    const int b  = m / (HSV*WSV);
    const int hw = m % (HSV*WSV);
    const int h = hw / WSV, w = hw % WSV;

    const bool act = lane < 48;
    const int ch = lane * 8;
    const int dd = (ch >> 7) + 1;

    float s[8];
#pragma unroll
    for (int j = 0; j < 8; ++j) s[j] = 0.f;

#pragma unroll
    for (int a = -1; a <= 1; ++a)
#pragma unroll
        for (int bb = -1; bb <= 1; ++bb) {
            const int h2_ = h + a*dd, w2_ = w + bb*dd;
            if (act && (unsigned)h2_ < (unsigned)HSV && (unsigned)w2_ < (unsigned)WSV) {
                h8 v = *(const h8*)(xc + (((size_t)b*HSV + h2_)*WSV + w2_)*DIV + ch);
#pragma unroll
                for (int j = 0; j < 8; ++j) s[j] += (float)v[j];
            }
        }

    float ps = 0.f, ps2 = 0.f;
#pragma unroll
    for (int j = 0; j < 8; ++j) { ps += s[j]; ps2 += s[j]*s[j]; }
#pragma unroll
    for (int off = 32; off > 0; off >>= 1) {
        ps  += __shfl_xor(ps,  off);
        ps2 += __shfl_xor(ps2, off);
    }
    const float mu   = ps * (1.f/384.f);
    const float var  = ps2 * (1.f/384.f) - mu*mu;
    const float rstd = rsqrtf(var + 1e-5f);

    if (act) {
        float4 g0 = *(const float4*)(g + ch);
        float4 g1 = *(const float4*)(g + ch + 4);
        float4 b0 = *(const float4*)(bta + ch);
        float4 b1 = *(const float4*)(bta + ch + 4);
        float gv[8] = {g0.x,g0.y,g0.z,g0.w,g1.x,g1.y,g1.z,g1.w};
        float bv[8] = {b0.x,b0.y,b0.z,b0.w,b1.x,b1.y,b1.z,b1.w};
        ushort8v o;
#pragma unroll
        for (int j = 0; j < 8; ++j)
            o[j] = f2bf((s[j] - mu)*rstd*gv[j] + bv[j]);
        *(ushort8v*)(yln + (size_t)m*DIV + ch) = o;
    }
}

// ---------------- K4: out(f32, Mx192) = yln @ WoutH^T + xh @ Wch^T  (MFMA, 128-row strips) ----------------
// async-STAGE: next-kb A/B global loads issued into regs right after the barrier; latency hides under MFMA.
__global__ __launch_bounds__(256) void gemm_out_mfma(
    const unsigned short* __restrict__ Yl, const unsigned short* __restrict__ WoutH,
    const unsigned short* __restrict__ xh, const unsigned short* __restrict__ Wch,
    float* __restrict__ out)
{
    __shared__ unsigned short As[128*64];     // 16 KB
    __shared__ unsigned short Bs[192*64];     // 24 KB
    const int t = threadIdx.x;
    const int m0 = blockIdx.x * 128;
    const int wid = t >> 6, lane = t & 63;
    const int wm = wid >> 1, wn = wid & 1;
    const int li = lane & 15, lg = lane >> 4;

    f32x4 acc[4][6];
#pragma unroll
    for (int i = 0; i < 4; ++i)
#pragma unroll
        for (int j = 0; j < 6; ++j) acc[i][j] = (f32x4){0.f,0.f,0.f,0.f};

    ushort8v pa[4], pb[6];
    loadRegs<128>(Yl + (size_t)m0*DIV, DIV, t, pa);
    loadRegs<192>(WoutH, DIV, t, pb);

    for (int kb = 0; kb < 9; ++kb) {
        writeRegs<128>(As, t, pa);
        writeRegs<192>(Bs, t, pb);
        __syncthreads();
        if (kb < 8) {
            const int k2 = kb + 1;
            if (k2 < 6) {
                loadRegs<128>(Yl + (size_t)m0*DIV + k2*64, DIV, t, pa);
                loadRegs<192>(WoutH + k2*64, DIV, t, pb);
            } else {
                loadRegs<128>(xh + (size_t)m0*DMV + (k2-6)*64, DMV, t, pa);
                loadRegs<192>(Wch + (k2-6)*64, DMV, t, pb);
            }
        }
#pragma unroll
        for (int ks = 0; ks < 2; ++ks) {
            short8v a[4], b[6];
#pragma unroll
            for (int mf = 0; mf < 4; ++mf) a[mf] = fragRead(As, wm*64 + mf*16 + li, ks*4 + lg);
#pragma unroll
            for (int nf = 0; nf < 6; ++nf) b[nf] = fragRead(Bs, wn*96 + nf*16 + li, ks*4 + lg);
#pragma unroll
            for (int mf = 0; mf < 4; ++mf)
#pragma unroll
                for (int nf = 0; nf < 6; ++nf)
                    acc[mf][nf] = __builtin_amdgcn_mfma_f32_16x16x32_bf16(a[mf], b[nf], acc[mf][nf], 0, 0, 0);
        }
        __syncthreads();
    }
#pragma unroll
    for (int mf = 0; mf < 4; ++mf)
#pragma unroll
        for (int nf = 0; nf < 6; ++nf)
#pragma unroll
            for (int i = 0; i < 4; ++i) {
                const int row = m0 + wm*64 + mf*16 + lg*4 + i;
                const int col = wn*96 + nf*16 + li;
                out[(size_t)row*DMV + col] = acc[mf][nf][i];
            }
}

extern "C" void kernel_launch(void* const* d_in, const int* in_sizes, int n_in,
                              void* d_out, int out_size, void* d_ws, size_t ws_size,
                              hipStream_t stream)
{
    const float* x      = (const float*)d_in[0];
    const float* W_in   = (const float*)d_in[1];
    const float* conv_w = (const float*)d_in[2];
    const float* conv_b = (const float*)d_in[3];
    const float* ln_g   = (const float*)d_in[11];
    const float* ln_b   = (const float*)d_in[12];
    const float* W_out  = (const float*)d_in[13];
    float* out = (float*)d_out;

    // ws (~90.2 MB): Wch | w2h | WinfH | WoutH | xh | xf(=yln).  xc aliases d_out.
    char* ws = (char*)d_ws;
    unsigned short* Wch   = (unsigned short*)(ws);              // 192*192 bf16
    h2*             w2h   = (h2*)(ws + 0x20000);                // 49*192 h2
    unsigned short* WinfH = (unsigned short*)(ws + 0x40000);    // 384*192 bf16
    unsigned short* WoutH = (unsigned short*)(ws + 0x80000);    // 192*384 bf16
    unsigned short* xh    = (unsigned short*)(ws + 0x100000);   // M*192 bf16
    _Float16*       xf    = (_Float16*)(ws + 0x2000000);        // M*384 f16 (reused as bf16 yln)
    _Float16*       xc    = (_Float16*)d_out;                   // M*384 f16 aliased on out

    prep_kernel  <<<dim3(301),          256, 0, stream>>>(W_out, W_in, conv_w,
                                                          Wch, w2h, WinfH, WoutH);
    gemm_in_mfma <<<dim3(MTOT/64),      256, 0, stream>>>(x, WinfH, xh, xf);
    dwconv_kernel<<<dim3(3456),         256, 0, stream>>>(xf, w2h, conv_b, xc);
    boxln_kernel <<<dim3(MTOT/4),       256, 0, stream>>>(xc, ln_g, ln_b,
                                                          (unsigned short*)xf);
    gemm_out_mfma<<<dim3(MTOT/128),     256, 0, stream>>>((const unsigned short*)xf,
                                                          WoutH, xh, Wch, out);
}

// Round 17
// 176.969 us; speedup vs baseline: 1.1151x; 1.0375x over previous
//
#include <hip/hip_runtime.h>
#include <cstddef>

#define B0V 8
#define HSV 96
#define WSV 96
#define DMV 192
#define DIV 384
#define MTOT (B0V*HSV*WSV)   // 73728

typedef __attribute__((ext_vector_type(8))) unsigned short ushort8v;
typedef __attribute__((ext_vector_type(8))) short short8v;
typedef __attribute__((ext_vector_type(4))) float f32x4;
typedef _Float16 h2 __attribute__((ext_vector_type(2)));
typedef _Float16 h8 __attribute__((ext_vector_type(8)));

__device__ __forceinline__ unsigned short f2bf(float f) {
    unsigned int i; __builtin_memcpy(&i, &f, 4);
    i += 0x7FFFu + ((i >> 16) & 1);
    return (unsigned short)(i >> 16);
}

// ---- LDS staging: tile stored [ROWS][64] bf16, 16B chunks XOR-swizzled by (row&7) ----
template<int ROWS>
__device__ __forceinline__ void stageBF16(const unsigned short* __restrict__ src, int ld,
                                          unsigned short* lds, int t) {
#pragma unroll
    for (int i = 0; i < ROWS*8/256; ++i) {
        const int cid = t + i*256;
        const int r = cid >> 3, cb = cid & 7;
        ushort8v sv = *(const ushort8v*)(src + (size_t)r*ld + cb*8);
        *(ushort8v*)((char*)lds + r*128 + ((cb ^ (r&7))<<4)) = sv;
    }
}
// split form: load global -> regs, and regs -> LDS (same indexing)
template<int ROWS>
__device__ __forceinline__ void loadRegs(const unsigned short* __restrict__ src, int ld,
                                         int t, ushort8v* r) {
#pragma unroll
    for (int i = 0; i < ROWS*8/256; ++i) {
        const int cid = t + i*256;
        const int rr = cid >> 3, cb = cid & 7;
        r[i] = *(const ushort8v*)(src + (size_t)rr*ld + cb*8);
    }
}
template<int ROWS>
__device__ __forceinline__ void writeRegs(unsigned short* lds, int t, const ushort8v* r) {
#pragma unroll
    for (int i = 0; i < ROWS*8/256; ++i) {
        const int cid = t + i*256;
        const int rr = cid >> 3, cb = cid & 7;
        *(ushort8v*)((char*)lds + rr*128 + ((cb ^ (rr&7))<<4)) = r[i];
    }
}
__device__ __forceinline__ short8v fragRead(const unsigned short* lds, int row, int kchunk) {
    return *(const short8v*)((const char*)lds + row*128 + ((kchunk ^ (row&7))<<4));
}

// ---------------- K0: fused prep — wc (192 blk) | wprep (37) | cvt Win (36) | cvt Wout (36) ----------------
__global__ __launch_bounds__(256) void prep_kernel(
    const float* __restrict__ Wout, const float* __restrict__ Win,
    const float* __restrict__ cw,
    unsigned short* __restrict__ Wch, h2* __restrict__ w2h,
    unsigned short* __restrict__ WinfH, unsigned short* __restrict__ WoutH)
{
    const int blk = blockIdx.x;
    const int t = threadIdx.x;
    if (blk < 192) {                       // Wch = W_out @ W_in_z  (bf16 out)
        __shared__ float wrow[384];
        for (int j = t; j < 384; j += 256) wrow[j] = Wout[(size_t)blk*384 + j];
        __syncthreads();
        if (t < 192) {
            float acc = 0.f;
#pragma unroll 4
            for (int j = 0; j < 384; ++j)
                acc += wrow[j] * Win[(size_t)(384 + j)*192 + t];
            Wch[(size_t)blk*192 + t] = f2bf(acc);
        }
    } else if (blk < 229) {                // conv-weight pack f32[384][49] -> h2[49][192]
        const int idx = (blk - 192)*256 + t;
        if (idx < 49*192) {
            const int tap = idx / 192, cp = idx % 192;
            h2 v;
            v[0] = (_Float16)cw[(size_t)(2*cp  )*49 + tap];
            v[1] = (_Float16)cw[(size_t)(2*cp+1)*49 + tap];
            w2h[idx] = v;
        }
    } else if (blk < 265) {                // Win_f -> bf16
        const int i = (blk - 229)*256 + t;
        if (i < 384*192/8) {
            const float4 f0 = *(const float4*)(Win + (size_t)i*8);
            const float4 f1 = *(const float4*)(Win + (size_t)i*8 + 4);
            ushort8v v;
            v[0]=f2bf(f0.x); v[1]=f2bf(f0.y); v[2]=f2bf(f0.z); v[3]=f2bf(f0.w);
            v[4]=f2bf(f1.x); v[5]=f2bf(f1.y); v[6]=f2bf(f1.z); v[7]=f2bf(f1.w);
            *(ushort8v*)(WinfH + (size_t)i*8) = v;
        }
    } else {                               // Wout -> bf16
        const int i = (blk - 265)*256 + t;
        if (i < 192*384/8) {
            const float4 f0 = *(const float4*)(Wout + (size_t)i*8);
            const float4 f1 = *(const float4*)(Wout + (size_t)i*8 + 4);
            ushort8v v;
            v[0]=f2bf(f0.x); v[1]=f2bf(f0.y); v[2]=f2bf(f0.z); v[3]=f2bf(f0.w);
            v[4]=f2bf(f1.x); v[5]=f2bf(f1.y); v[6]=f2bf(f1.z); v[7]=f2bf(f1.w);
            *(ushort8v*)(WoutH + (size_t)i*8) = v;
        }
    }
}

// ---------------- K1: xf(f16, Mx384) = x(f32) @ W_in_f^T(bf16)  (MFMA, 64-row strips) ----------------
// A resident; B streamed with async-STAGE register prefetch (next-B load hides under MFMA).
__global__ __launch_bounds__(256) void gemm_in_mfma(
    const float* __restrict__ x, const unsigned short* __restrict__ Wh,
    unsigned short* __restrict__ xh, _Float16* __restrict__ xf)
{
    __shared__ unsigned short As[3*64*64];    // 24 KB, resident
    __shared__ unsigned short Bs[128*64];     // 16 KB, streamed
    const int t = threadIdx.x;
    const int m0 = blockIdx.x * 64;
    const int wid = t >> 6, lane = t & 63;
    const int li = lane & 15, lg = lane >> 4;

    // stage A (64x192) once: f32 -> bf16 -> LDS swizzled + xh global
#pragma unroll
    for (int kb = 0; kb < 3; ++kb) {
#pragma unroll
        for (int i = 0; i < 2; ++i) {
            const int cid = t + i*256;
            const int r = cid >> 3, cb = cid & 7;
            const float* p = x + (size_t)(m0 + r)*DMV + kb*64 + cb*8;
            float4 f0 = *(const float4*)p;
            float4 f1 = *(const float4*)(p+4);
            ushort8v sv;
            sv[0]=f2bf(f0.x); sv[1]=f2bf(f0.y); sv[2]=f2bf(f0.z); sv[3]=f2bf(f0.w);
            sv[4]=f2bf(f1.x); sv[5]=f2bf(f1.y); sv[6]=f2bf(f1.z); sv[7]=f2bf(f1.w);
            *(ushort8v*)((char*)(As + kb*64*64) + r*128 + ((cb ^ (r&7))<<4)) = sv;
            *(ushort8v*)(xh + (size_t)(m0 + r)*DMV + kb*64 + cb*8) = sv;
        }
    }

    ushort8v pb[4];
    loadRegs<128>(Wh, DMV, t, pb);            // (n0=0, kb=0)

    f32x4 acc[4][2];
    for (int it = 0; it < 9; ++it) {
        const int n0i = it / 3, kb = it - n0i*3;
        const int n0 = n0i * 128;
        if (kb == 0) {
#pragma unroll
            for (int i = 0; i < 4; ++i)
#pragma unroll
                for (int j = 0; j < 2; ++j) acc[i][j] = (f32x4){0.f,0.f,0.f,0.f};
        }
        writeRegs<128>(Bs, t, pb);
        __syncthreads();
        if (it < 8) {
            const int itn = it + 1;
            loadRegs<128>(Wh + (size_t)((itn/3)*128)*DMV + (itn%3)*64, DMV, t, pb);
        }
#pragma unroll
        for (int ks = 0; ks < 2; ++ks) {
            short8v a[4], b[2];
#pragma unroll
            for (int mf = 0; mf < 4; ++mf)
                a[mf] = fragRead(As + kb*64*64, mf*16 + li, ks*4 + lg);
#pragma unroll
            for (int nf = 0; nf < 2; ++nf)
                b[nf] = fragRead(Bs, wid*32 + nf*16 + li, ks*4 + lg);
#pragma unroll
            for (int mf = 0; mf < 4; ++mf)
#pragma unroll
                for (int nf = 0; nf < 2; ++nf)
                    acc[mf][nf] = __builtin_amdgcn_mfma_f32_16x16x32_bf16(a[mf], b[nf], acc[mf][nf], 0, 0, 0);
        }
        __syncthreads();
        if (kb == 2) {
#pragma unroll
            for (int mf = 0; mf < 4; ++mf)
#pragma unroll
                for (int nf = 0; nf < 2; ++nf)
#pragma unroll
                    for (int i = 0; i < 4; ++i) {
                        const int row = m0 + mf*16 + lg*4 + i;
                        const int col = n0 + wid*32 + nf*16 + li;
                        xf[(size_t)row*DIV + col] = (_Float16)acc[mf][nf][i];
                    }
        }
    }
}

// ---------------- K2: depthwise 7x7 conv — R14 exact: R6 tiling + XCD-chunked swizzle ----------------
__global__ __launch_bounds__(256) void dwconv_kernel(
    const _Float16* __restrict__ xf, const h2* __restrict__ w2h,
    const float* __restrict__ cb, _Float16* __restrict__ xc)
{
    const int id  = blockIdx.x;
    const int swz = (id & 7) * 432 + (id >> 3);
    const int b    = swz / 432;
    const int rem  = swz - b*432;
    const int cg   = rem / 72;
    const int tile = rem - cg*72;
    const int th = tile / 6, tw = tile % 6;
    const int h0 = th*8, w0 = tw*16;
    const int c0 = cg*64;

    __shared__ _Float16 patch[14*22*64];    // 38.5 KB, linear (conflict-free, measured)
    const int t = threadIdx.x;
    for (int idx = t; idx < 308*8; idx += 256) {
        const int sp = idx >> 3, c8 = idx & 7;
        const int ih = sp / 22, iw = sp - ih*22;
        const int gh = h0 - 3 + ih, gw = w0 - 3 + iw;
        ushort8v v;
#pragma unroll
        for (int j = 0; j < 8; ++j) v[j] = 0;
        if ((unsigned)gh < (unsigned)HSV && (unsigned)gw < (unsigned)WSV)
            v = *(const ushort8v*)(xf + (((size_t)b*HSV + gh)*WSV + gw)*DIV + c0 + c8*8);
        *(ushort8v*)(patch + sp*64 + c8*8) = v;
    }
    __syncthreads();

    const int cp = t & 31;
    const int wq = t >> 5;

    h2 wreg[49];
    const h2* wp = w2h + (c0 >> 1) + cp;
#pragma unroll
    for (int k = 0; k < 49; ++k) wreg[k] = wp[k*192];

    h2 biasv;
    biasv[0] = (_Float16)cb[c0 + 2*cp];
    biasv[1] = (_Float16)cb[c0 + 2*cp + 1];
    h2 acc[8][2];
#pragma unroll
    for (int i = 0; i < 8; ++i) { acc[i][0] = biasv; acc[i][1] = biasv; }

    const h2* prow = (const h2*)patch;
#pragma unroll
    for (int ih = 0; ih < 14; ++ih) {
        h2 r[8];
#pragma unroll
        for (int j = 0; j < 8; ++j)
            r[j] = prow[(ih*22 + wq*2 + j)*32 + cp];
#pragma unroll
        for (int kw = 0; kw < 7; ++kw) {
#pragma unroll
            for (int oh = 0; oh < 8; ++oh) {
                const int kh = ih - oh;
                if (kh >= 0 && kh < 7) {
                    acc[oh][0] += wreg[kh*7 + kw] * r[kw];
                    acc[oh][1] += wreg[kh*7 + kw] * r[kw + 1];
                }
            }
        }
    }
    h2* xcp = (h2*)xc;
#pragma unroll
    for (int oh = 0; oh < 8; ++oh)
#pragma unroll
        for (int j = 0; j < 2; ++j)
            xcp[((((size_t)b*HSV + h0+oh)*WSV + (w0 + wq*2 + j))*DIV + c0)/2 + cp] = acc[oh][j];
}

// ---------------- K3: dilated 3x3 box-sum + LayerNorm — 2 pixels per wave + XCD swizzle ----------------
// grid 9216; swz=(id&7)*1152+id>>3 (bijective). Wave handles pixels m0, m0+1 with
// interleaved independent load chains (2x memory-level parallelism).
__global__ __launch_bounds__(256) void boxln_kernel(
    const _Float16* __restrict__ xc,
    const float* __restrict__ g, const float* __restrict__ bta,
    unsigned short* __restrict__ yln)
{
    const int wid  = threadIdx.x >> 6;
    const int lane = threadIdx.x & 63;
    const int id  = blockIdx.x;
    const int swz = (id & 7) * 1152 + (id >> 3);
    const int m0 = swz * 8 + wid * 2;            // two consecutive pixels
    const int m1 = m0 + 1;

    const int b0 = m0 / (HSV*WSV), hw0 = m0 % (HSV*WSV);
    const int h0 = hw0 / WSV, w0 = hw0 % WSV;
    const int b1 = m1 / (HSV*WSV), hw1 = m1 % (HSV*WSV);
    const int h1 = hw1 / WSV, w1 = hw1 % WSV;

    const bool act = lane < 48;
    const int ch = lane * 8;
    const int dd = (ch >> 7) + 1;

    float s0[8], s1[8];
#pragma unroll
    for (int j = 0; j < 8; ++j) { s0[j] = 0.f; s1[j] = 0.f; }

#pragma unroll
    for (int a = -1; a <= 1; ++a)
#pragma unroll
        for (int bb = -1; bb <= 1; ++bb) {
            const int ha = h0 + a*dd, wa = w0 + bb*dd;
            const int hb = h1 + a*dd, wb = w1 + bb*dd;
            const bool va = act && (unsigned)ha < (unsigned)HSV && (unsigned)wa < (unsigned)WSV;
            const bool vb = act && (unsigned)hb < (unsigned)HSV && (unsigned)wb < (unsigned)WSV;
            h8 u0, u1;
            if (va) u0 = *(const h8*)(xc + (((size_t)b0*HSV + ha)*WSV + wa)*DIV + ch);
            if (vb) u1 = *(const h8*)(xc + (((size_t)b1*HSV + hb)*WSV + wb)*DIV + ch);
            if (va) {
#pragma unroll
                for (int j = 0; j < 8; ++j) s0[j] += (float)u0[j];
            }
            if (vb) {
#pragma unroll
                for (int j = 0; j < 8; ++j) s1[j] += (float)u1[j];
            }
        }

    float pa = 0.f, pa2 = 0.f, pb = 0.f, pb2 = 0.f;
#pragma unroll
    for (int j = 0; j < 8; ++j) {
        pa += s0[j]; pa2 += s0[j]*s0[j];
        pb += s1[j]; pb2 += s1[j]*s1[j];
    }
#pragma unroll
    for (int off = 32; off > 0; off >>= 1) {
        pa  += __shfl_xor(pa,  off);
        pa2 += __shfl_xor(pa2, off);
        pb  += __shfl_xor(pb,  off);
        pb2 += __shfl_xor(pb2, off);
    }
    const float mu0   = pa * (1.f/384.f);
    const float rstd0 = rsqrtf(pa2 * (1.f/384.f) - mu0*mu0 + 1e-5f);
    const float mu1   = pb * (1.f/384.f);
    const float rstd1 = rsqrtf(pb2 * (1.f/384.f) - mu1*mu1 + 1e-5f);

    if (act) {
        float4 g0 = *(const float4*)(g + ch);
        float4 g1 = *(const float4*)(g + ch + 4);
        float4 b0v = *(const float4*)(bta + ch);
        float4 b1v = *(const float4*)(bta + ch + 4);
        float gv[8] = {g0.x,g0.y,g0.z,g0.w,g1.x,g1.y,g1.z,g1.w};
        float bv[8] = {b0v.x,b0v.y,b0v.z,b0v.w,b1v.x,b1v.y,b1v.z,b1v.w};
        ushort8v o0, o1;
#pragma unroll
        for (int j = 0; j < 8; ++j) {
            o0[j] = f2bf((s0[j] - mu0)*rstd0*gv[j] + bv[j]);
            o1[j] = f2bf((s1[j] - mu1)*rstd1*gv[j] + bv[j]);
        }
        *(ushort8v*)(yln + (size_t)m0*DIV + ch) = o0;
        *(ushort8v*)(yln + (size_t)m1*DIV + ch) = o1;
    }
}

// ---------------- K4: out(f32, Mx192) = yln @ WoutH^T + xh @ Wch^T  (MFMA, 128-row strips) ----------------
// async-STAGE: next-kb A/B global loads issued into regs right after the barrier; latency hides under MFMA.
__global__ __launch_bounds__(256) void gemm_out_mfma(
    const unsigned short* __restrict__ Yl, const unsigned short* __restrict__ WoutH,
    const unsigned short* __restrict__ xh, const unsigned short* __restrict__ Wch,
    float* __restrict__ out)
{
    __shared__ unsigned short As[128*64];     // 16 KB
    __shared__ unsigned short Bs[192*64];     // 24 KB
    const int t = threadIdx.x;
    const int m0 = blockIdx.x * 128;
    const int wid = t >> 6, lane = t & 63;
    const int wm = wid >> 1, wn = wid & 1;
    const int li = lane & 15, lg = lane >> 4;

    f32x4 acc[4][6];
#pragma unroll
    for (int i = 0; i < 4; ++i)
#pragma unroll
        for (int j = 0; j < 6; ++j) acc[i][j] = (f32x4){0.f,0.f,0.f,0.f};

    ushort8v pa[4], pb[6];
    loadRegs<128>(Yl + (size_t)m0*DIV, DIV, t, pa);
    loadRegs<192>(WoutH, DIV, t, pb);

    for (int kb = 0; kb < 9; ++kb) {
        writeRegs<128>(As, t, pa);
        writeRegs<192>(Bs, t, pb);
        __syncthreads();
        if (kb < 8) {
            const int k2 = kb + 1;
            if (k2 < 6) {
                loadRegs<128>(Yl + (size_t)m0*DIV + k2*64, DIV, t, pa);
                loadRegs<192>(WoutH + k2*64, DIV, t, pb);
            } else {
                loadRegs<128>(xh + (size_t)m0*DMV + (k2-6)*64, DMV, t, pa);
                loadRegs<192>(Wch + (k2-6)*64, DMV, t, pb);
            }
        }
#pragma unroll
        for (int ks = 0; ks < 2; ++ks) {
            short8v a[4], b[6];
#pragma unroll
            for (int mf = 0; mf < 4; ++mf) a[mf] = fragRead(As, wm*64 + mf*16 + li, ks*4 + lg);
#pragma unroll
            for (int nf = 0; nf < 6; ++nf) b[nf] = fragRead(Bs, wn*96 + nf*16 + li, ks*4 + lg);
#pragma unroll
            for (int mf = 0; mf < 4; ++mf)
#pragma unroll
                for (int nf = 0; nf < 6; ++nf)
                    acc[mf][nf] = __builtin_amdgcn_mfma_f32_16x16x32_bf16(a[mf], b[nf], acc[mf][nf], 0, 0, 0);
        }
        __syncthreads();
    }
#pragma unroll
    for (int mf = 0; mf < 4; ++mf)
#pragma unroll
        for (int nf = 0; nf < 6; ++nf)
#pragma unroll
            for (int i = 0; i < 4; ++i) {
                const int row = m0 + wm*64 + mf*16 + lg*4 + i;
                const int col = wn*96 + nf*16 + li;
                out[(size_t)row*DMV + col] = acc[mf][nf][i];
            }
}

extern "C" void kernel_launch(void* const* d_in, const int* in_sizes, int n_in,
                              void* d_out, int out_size, void* d_ws, size_t ws_size,
                              hipStream_t stream)
{
    const float* x      = (const float*)d_in[0];
    const float* W_in   = (const float*)d_in[1];
    const float* conv_w = (const float*)d_in[2];
    const float* conv_b = (const float*)d_in[3];
    const float* ln_g   = (const float*)d_in[11];
    const float* ln_b   = (const float*)d_in[12];
    const float* W_out  = (const float*)d_in[13];
    float* out = (float*)d_out;

    // ws (~90.2 MB): Wch | w2h | WinfH | WoutH | xh | xf(=yln).  xc aliases d_out.
    char* ws = (char*)d_ws;
    unsigned short* Wch   = (unsigned short*)(ws);              // 192*192 bf16
    h2*             w2h   = (h2*)(ws + 0x20000);                // 49*192 h2
    unsigned short* WinfH = (unsigned short*)(ws + 0x40000);    // 384*192 bf16
    unsigned short* WoutH = (unsigned short*)(ws + 0x80000);    // 192*384 bf16
    unsigned short* xh    = (unsigned short*)(ws + 0x100000);   // M*192 bf16
    _Float16*       xf    = (_Float16*)(ws + 0x2000000);        // M*384 f16 (reused as bf16 yln)
    _Float16*       xc    = (_Float16*)d_out;                   // M*384 f16 aliased on out

    prep_kernel  <<<dim3(301),          256, 0, stream>>>(W_out, W_in, conv_w,
                                                          Wch, w2h, WinfH, WoutH);
    gemm_in_mfma <<<dim3(MTOT/64),      256, 0, stream>>>(x, WinfH, xh, xf);
    dwconv_kernel<<<dim3(3456),         256, 0, stream>>>(xf, w2h, conv_b, xc);
    boxln_kernel <<<dim3(MTOT/8),       256, 0, stream>>>(xc, ln_g, ln_b,
                                                          (unsigned short*)xf);
    gemm_out_mfma<<<dim3(MTOT/128),     256, 0, stream>>>((const unsigned short*)xf,
                                                          WoutH, xh, Wch, out);
}